// Round 1
// baseline (318.958 us; speedup 1.0000x reference)
//
#include <hip/hip_runtime.h>

// ---------------- fixed problem shape ----------------
#define BATCH  2
#define SEQ    2048
#define DMODEL 1024
#define NHEAD  16
#define HDIM   64
#define NROWS  (BATCH * SEQ)   // 4096
#define QKVC   (3 * DMODEL)    // 3072

typedef float f32x4 __attribute__((ext_vector_type(4)));
typedef short s16x8 __attribute__((ext_vector_type(8)));

__device__ __forceinline__ unsigned short f2bf(float f) {
  unsigned int u = __float_as_uint(f);
  u = (u + 0x7FFFu + ((u >> 16) & 1u)) >> 16;   // RNE
  return (unsigned short)u;
}
__device__ __forceinline__ float bf2f(unsigned short s) {
  return __uint_as_float(((unsigned int)s) << 16);
}

// ---------------------------------------------------------------------------
// 1) row-normalize f32 weight rows (len 1024) -> bf16  w_hat = w/(eps+||w||/32)*(1/32)
// ---------------------------------------------------------------------------
__global__ __launch_bounds__(256) void k_wnorm(const float* __restrict__ W,
                                               unsigned short* __restrict__ Wh) {
  const int row = blockIdx.x, tid = threadIdx.x;
  const float4* rp = (const float4*)(W + (size_t)row * DMODEL);
  float4 v = rp[tid];                              // 256 threads x 4 = 1024
  float ss = v.x * v.x + v.y * v.y + v.z * v.z + v.w * v.w;
#pragma unroll
  for (int m = 1; m < 64; m <<= 1) ss += __shfl_xor(ss, m);
  __shared__ float part[4];
  if ((tid & 63) == 0) part[tid >> 6] = ss;
  __syncthreads();
  const float tot = part[0] + part[1] + part[2] + part[3];
  const float scale = 0.03125f / (1e-4f + sqrtf(tot) * 0.03125f);
  unsigned short* op = Wh + (size_t)row * DMODEL + tid * 4;
  op[0] = f2bf(v.x * scale); op[1] = f2bf(v.y * scale);
  op[2] = f2bf(v.z * scale); op[3] = f2bf(v.w * scale);
}

// ---------------------------------------------------------------------------
// 2) f32 -> bf16 cast, 4 elems/thread
// ---------------------------------------------------------------------------
__global__ __launch_bounds__(256) void k_cast(const float* __restrict__ X,
                                              unsigned short* __restrict__ Xb) {
  const int i = blockIdx.x * 256 + threadIdx.x;
  const float4 v = ((const float4*)X)[i];
  ushort4 o = { f2bf(v.x), f2bf(v.y), f2bf(v.z), f2bf(v.w) };
  ((ushort4*)Xb)[i] = o;
}

// ---------------------------------------------------------------------------
// 3) C[M][N] = A[M][K] * B[N][K]^T   (bf16 in, f32 acc), 128x128x64 tile, 4 waves
//    m93-verified structure; LDS rows padded to 88 shorts (176B, 16B-aligned,
//    ~2-way bank aliasing on ds_read_b128 which is free per m136).
// ---------------------------------------------------------------------------
#define LDP 88
template <int WRITE_BF16>
__global__ __launch_bounds__(256) void k_gemm_bt(const unsigned short* __restrict__ A,
                                                 const unsigned short* __restrict__ Bm,
                                                 void* __restrict__ Cv,
                                                 int M, int N, int K) {
  __shared__ unsigned short As[128 * LDP];
  __shared__ unsigned short Bs[128 * LDP];
  const int tid = threadIdx.x;
  const int nbn = N >> 7;
  const int bm = (blockIdx.x / nbn) << 7;
  const int bn = (blockIdx.x % nbn) << 7;
  const int wave = tid >> 6, lane = tid & 63;
  const int wr = (wave >> 1) << 6, wc = (wave & 1) << 6;  // 2x2 wave grid, 64x64 each
  const int l16 = lane & 15, lg = lane >> 4;

  f32x4 acc[4][4];
#pragma unroll
  for (int m = 0; m < 4; ++m)
#pragma unroll
    for (int n = 0; n < 4; ++n) acc[m][n] = (f32x4){0.f, 0.f, 0.f, 0.f};

  for (int k0 = 0; k0 < K; k0 += 64) {
    // register-stage the 128x64 A and B tiles (16B/lane x 4 iters)
    s16x8 ra[4], rb[4];
#pragma unroll
    for (int it = 0; it < 4; ++it) {
      const int c = it * 256 + tid;
      const int r = c >> 3, col = (c & 7) << 3;
      ra[it] = *(const s16x8*)(A + (size_t)(bm + r) * K + k0 + col);
      rb[it] = *(const s16x8*)(Bm + (size_t)(bn + r) * K + k0 + col);
    }
    __syncthreads();   // previous tile fully consumed
#pragma unroll
    for (int it = 0; it < 4; ++it) {
      const int c = it * 256 + tid;
      const int r = c >> 3, col = (c & 7) << 3;
      *(s16x8*)(As + r * LDP + col) = ra[it];
      *(s16x8*)(Bs + r * LDP + col) = rb[it];
    }
    __syncthreads();
#pragma unroll
    for (int ks = 0; ks < 2; ++ks) {
      s16x8 af[4], bq[4];
#pragma unroll
      for (int m = 0; m < 4; ++m)
        af[m] = *(const s16x8*)(As + (wr + m * 16 + l16) * LDP + ks * 32 + lg * 8);
#pragma unroll
      for (int n = 0; n < 4; ++n)
        bq[n] = *(const s16x8*)(Bs + (wc + n * 16 + l16) * LDP + ks * 32 + lg * 8);
#pragma unroll
      for (int m = 0; m < 4; ++m)
#pragma unroll
        for (int n = 0; n < 4; ++n)
          acc[m][n] = __builtin_amdgcn_mfma_f32_16x16x32_bf16(af[m], bq[n], acc[m][n], 0, 0, 0);
    }
  }
  // D layout (verified m89/m91): row = 4*lg + r, col = l16
  if (WRITE_BF16) {
    unsigned short* C = (unsigned short*)Cv;
#pragma unroll
    for (int m = 0; m < 4; ++m)
#pragma unroll
      for (int n = 0; n < 4; ++n)
#pragma unroll
        for (int r = 0; r < 4; ++r)
          C[(size_t)(bm + wr + m * 16 + lg * 4 + r) * N + (bn + wc + n * 16 + l16)] =
              f2bf(acc[m][n][r]);
  } else {
    float* C = (float*)Cv;
#pragma unroll
    for (int m = 0; m < 4; ++m)
#pragma unroll
      for (int n = 0; n < 4; ++n)
#pragma unroll
        for (int r = 0; r < 4; ++r)
          C[(size_t)(bm + wr + m * 16 + lg * 4 + r) * N + (bn + wc + n * 16 + l16)] =
              acc[m][n][r];
  }
}

// ---------------------------------------------------------------------------
// 4) normalize q,k head-vectors (hd=64) in-place in qkv cols [0,2048)
//    scale = 1/(eps + ||v||/8);  8-thread groups per head-vector
// ---------------------------------------------------------------------------
__global__ __launch_bounds__(256) void k_qknorm(unsigned short* __restrict__ qkv) {
  const int row = blockIdx.x, tid = threadIdx.x;
  const int hv = tid >> 3, g = tid & 7;   // 32 head-vectors (16 q + 16 k)
  const int base = (hv < 16) ? (hv * HDIM) : (DMODEL + (hv - 16) * HDIM);
  unsigned short* p = qkv + (size_t)row * QKVC + base + g * 8;
  s16x8 v = *(const s16x8*)p;
  float f[8];
  float ss = 0.f;
#pragma unroll
  for (int j = 0; j < 8; ++j) { f[j] = bf2f((unsigned short)v[j]); ss += f[j] * f[j]; }
  ss += __shfl_xor(ss, 1); ss += __shfl_xor(ss, 2); ss += __shfl_xor(ss, 4);
  const float scale = 1.f / (1e-4f + sqrtf(ss) * 0.125f);
  s16x8 o;
#pragma unroll
  for (int j = 0; j < 8; ++j) o[j] = (short)f2bf(f[j] * scale);
  *(s16x8*)p = o;
}

// ---------------------------------------------------------------------------
// 5) V transpose: qkv v-part -> Vt[bh][d][t]  (so PV B-frags are contiguous 16B)
// ---------------------------------------------------------------------------
__global__ __launch_bounds__(256) void k_vtrans(const unsigned short* __restrict__ qkv,
                                                unsigned short* __restrict__ Vt) {
  const int tt = blockIdx.x & 31, bh = blockIdx.x >> 5;
  const int b = bh >> 4, h = bh & 15;
  const int t0 = tt * 64;
  __shared__ unsigned short tile[64][80];   // 160B row stride, 16B-aligned
  const int tid = threadIdx.x;
#pragma unroll
  for (int half = 0; half < 2; ++half) {
    const int tl = half * 32 + (tid >> 3), part = tid & 7;
    s16x8 v = *(const s16x8*)(qkv + (size_t)(b * SEQ + t0 + tl) * QKVC + 2 * DMODEL +
                              h * HDIM + part * 8);
    *(s16x8*)(&tile[tl][part * 8]) = v;
  }
  __syncthreads();
#pragma unroll
  for (int half = 0; half < 2; ++half) {
    const int d = half * 32 + (tid >> 3), tp = tid & 7;
    s16x8 o;
#pragma unroll
    for (int j = 0; j < 8; ++j) o[j] = (short)tile[tp * 8 + j][d];
    *(s16x8*)(Vt + (size_t)(bh * HDIM + d) * SEQ + t0 + tp * 8) = o;
  }
}

// ---------------------------------------------------------------------------
// 6) flash attention: block = (bh, 64-query tile), 4 waves x 16 queries each.
//    KB=64 keys/iter; QK^T and PV in 16x16x32 bf16 MFMA; online softmax via
//    16-lane shfl_xor row reduces; P transposed through wave-private LDS.
// ---------------------------------------------------------------------------
__global__ __launch_bounds__(256) void k_attn(const unsigned short* __restrict__ qkv,
                                              const unsigned short* __restrict__ Vt,
                                              unsigned short* __restrict__ O) {
  const int qt = blockIdx.x & 31, bh = blockIdx.x >> 5;
  const int b = bh >> 4, h = bh & 15;
  const int wave = threadIdx.x >> 6, lane = threadIdx.x & 63;
  const int l16 = lane & 15, lg = lane >> 4;
  const int q0 = qt * 64 + wave * 16;

  __shared__ unsigned short P[4][16 * LDP];   // wave-private P tiles
  unsigned short* Pw = &P[wave][0];

  // Q fragments (row = l16, k = 8*lg + j), fixed for the whole kernel
  const size_t qbase = (size_t)(b * SEQ + q0 + l16) * QKVC + h * HDIM;
  const s16x8 aq0 = *(const s16x8*)(qkv + qbase + lg * 8);
  const s16x8 aq1 = *(const s16x8*)(qkv + qbase + 32 + lg * 8);

  f32x4 o[4];
#pragma unroll
  for (int n = 0; n < 4; ++n) o[n] = (f32x4){0.f, 0.f, 0.f, 0.f};
  float mrow[4] = {-1e30f, -1e30f, -1e30f, -1e30f};
  float lrow[4] = {0.f, 0.f, 0.f, 0.f};

  for (int kt = 0; kt < SEQ; kt += 64) {
    // ---- S = Q*K^T * scale (4 key sub-tiles of 16) ----
    f32x4 s[4];
#pragma unroll
    for (int sub = 0; sub < 4; ++sub) {
      const size_t kbase =
          (size_t)(b * SEQ + kt + sub * 16 + l16) * QKVC + DMODEL + h * HDIM;
      const s16x8 bk0 = *(const s16x8*)(qkv + kbase + lg * 8);
      const s16x8 bk1 = *(const s16x8*)(qkv + kbase + 32 + lg * 8);
      f32x4 z = (f32x4){0.f, 0.f, 0.f, 0.f};
      z = __builtin_amdgcn_mfma_f32_16x16x32_bf16(aq0, bk0, z, 0, 0, 0);
      z = __builtin_amdgcn_mfma_f32_16x16x32_bf16(aq1, bk1, z, 0, 0, 0);
      s[sub] = z * 0.125f;   // 1/sqrt(64)
    }
    // ---- online softmax; row r lives on lanes sharing lg, cols on l16 ----
    float corr[4];
#pragma unroll
    for (int r = 0; r < 4; ++r) {
      float tm = fmaxf(fmaxf(s[0][r], s[1][r]), fmaxf(s[2][r], s[3][r]));
#pragma unroll
      for (int msk = 1; msk <= 8; msk <<= 1) tm = fmaxf(tm, __shfl_xor(tm, msk));
      const float mnew = fmaxf(mrow[r], tm);
      const float c = __expf(mrow[r] - mnew);
      mrow[r] = mnew;
      float rs = 0.f;
#pragma unroll
      for (int sub = 0; sub < 4; ++sub) {
        const float pv = __expf(s[sub][r] - mnew);
        s[sub][r] = pv;
        rs += pv;
      }
#pragma unroll
      for (int msk = 1; msk <= 8; msk <<= 1) rs += __shfl_xor(rs, msk);
      lrow[r] = lrow[r] * c + rs;
      corr[r] = c;
    }
#pragma unroll
    for (int n = 0; n < 4; ++n) {
      o[n][0] *= corr[0]; o[n][1] *= corr[1];
      o[n][2] *= corr[2]; o[n][3] *= corr[3];
    }
    // ---- P (D-layout) -> LDS -> A-fragments (wave-private; compiler orders) ----
#pragma unroll
    for (int sub = 0; sub < 4; ++sub)
#pragma unroll
      for (int r = 0; r < 4; ++r)
        Pw[(lg * 4 + r) * LDP + sub * 16 + l16] = f2bf(s[sub][r]);
    const s16x8 pa0 = *(const s16x8*)(Pw + l16 * LDP + lg * 8);
    const s16x8 pa1 = *(const s16x8*)(Pw + l16 * LDP + 32 + lg * 8);
    // ---- O += P * V  (B-frags from Vt rows, contiguous in key) ----
#pragma unroll
    for (int n = 0; n < 4; ++n) {
      const size_t vbase = (size_t)(bh * HDIM + n * 16 + l16) * SEQ + kt;
      const s16x8 bv0 = *(const s16x8*)(Vt + vbase + lg * 8);
      const s16x8 bv1 = *(const s16x8*)(Vt + vbase + 32 + lg * 8);
      o[n] = __builtin_amdgcn_mfma_f32_16x16x32_bf16(pa0, bv0, o[n], 0, 0, 0);
      o[n] = __builtin_amdgcn_mfma_f32_16x16x32_bf16(pa1, bv1, o[n], 0, 0, 0);
    }
  }
  // ---- epilogue: O[b][t][h*64+d] bf16 ----
#pragma unroll
  for (int r = 0; r < 4; ++r) {
    const float inv = 1.f / lrow[r];
    const int q = q0 + lg * 4 + r;
#pragma unroll
    for (int n = 0; n < 4; ++n)
      O[(size_t)(b * SEQ + q) * DMODEL + h * HDIM + n * 16 + l16] =
          f2bf(o[n][r] * inv);
  }
}

// ---------------------------------------------------------------------------
// launch: ws layout (bytes): Wq[0,6M) Wo[6M,8M) Xb[8M,16M) QKV[16M,40M) Vt[40M,48M)
// attn output O aliases Xb (x_bf16 is dead after the QKV GEMM). Total 50.3MB.
// ---------------------------------------------------------------------------
extern "C" void kernel_launch(void* const* d_in, const int* in_sizes, int n_in,
                              void* d_out, int out_size, void* d_ws, size_t ws_size,
                              hipStream_t stream) {
  const float* x    = (const float*)d_in[0];
  const float* wqkv = (const float*)d_in[1];
  const float* wout = (const float*)d_in[2];
  char* ws = (char*)d_ws;
  unsigned short* Wq  = (unsigned short*)(ws);              // 3072x1024 bf16
  unsigned short* Wo  = (unsigned short*)(ws + 6291456);    // 1024x1024 bf16
  unsigned short* Xb  = (unsigned short*)(ws + 8388608);    // 4096x1024 bf16 (later attn O)
  unsigned short* QKV = (unsigned short*)(ws + 16777216);   // 4096x3072 bf16
  unsigned short* Vt  = (unsigned short*)(ws + 41943040);   // 32x64x2048 bf16
  (void)in_sizes; (void)n_in; (void)out_size; (void)ws_size;

  k_wnorm<<<QKVC, 256, 0, stream>>>(wqkv, Wq);
  k_wnorm<<<DMODEL, 256, 0, stream>>>(wout, Wo);
  k_cast<<<(NROWS * DMODEL) / 1024, 256, 0, stream>>>(x, Xb);
  k_gemm_bt<1><<<(NROWS / 128) * (QKVC / 128), 256, 0, stream>>>(
      Xb, Wq, (void*)QKV, NROWS, QKVC, DMODEL);
  k_qknorm<<<NROWS, 256, 0, stream>>>(QKV);
  k_vtrans<<<BATCH * NHEAD * (SEQ / 64), 256, 0, stream>>>(QKV, Vt);
  k_attn<<<BATCH * NHEAD * (SEQ / 64), 256, 0, stream>>>(QKV, Vt, Xb);
  k_gemm_bt<0><<<(NROWS / 128) * (DMODEL / 128), 256, 0, stream>>>(
      Xb, Wo, d_out, NROWS, DMODEL, DMODEL);
}

// Round 2
// 317.768 us; speedup vs baseline: 1.0037x; 1.0037x over previous
//
#include <hip/hip_runtime.h>

// ---------------- fixed problem shape ----------------
#define BATCH  2
#define SEQ    2048
#define DMODEL 1024
#define NHEAD  16
#define HDIM   64
#define NROWS  (BATCH * SEQ)   // 4096
#define QKVC   (3 * DMODEL)    // 3072

typedef float f32x4 __attribute__((ext_vector_type(4)));
typedef short s16x8 __attribute__((ext_vector_type(8)));
typedef short s16x4 __attribute__((ext_vector_type(4)));

__device__ __forceinline__ unsigned short f2bf(float f) {
  unsigned int u = __float_as_uint(f);
  u = (u + 0x7FFFu + ((u >> 16) & 1u)) >> 16;   // RNE
  return (unsigned short)u;
}
__device__ __forceinline__ float bf2f(unsigned short s) {
  return __uint_as_float(((unsigned int)s) << 16);
}

// ---------------------------------------------------------------------------
// 1) row-normalize f32 weight rows (len 1024) -> bf16  w_hat = w/(eps+||w||/32)*(1/32)
// ---------------------------------------------------------------------------
__global__ __launch_bounds__(256) void k_wnorm(const float* __restrict__ W,
                                               unsigned short* __restrict__ Wh) {
  const int row = blockIdx.x, tid = threadIdx.x;
  const float4* rp = (const float4*)(W + (size_t)row * DMODEL);
  float4 v = rp[tid];                              // 256 threads x 4 = 1024
  float ss = v.x * v.x + v.y * v.y + v.z * v.z + v.w * v.w;
#pragma unroll
  for (int m = 1; m < 64; m <<= 1) ss += __shfl_xor(ss, m);
  __shared__ float part[4];
  if ((tid & 63) == 0) part[tid >> 6] = ss;
  __syncthreads();
  const float tot = part[0] + part[1] + part[2] + part[3];
  const float scale = 0.03125f / (1e-4f + sqrtf(tot) * 0.03125f);
  unsigned short* op = Wh + (size_t)row * DMODEL + tid * 4;
  op[0] = f2bf(v.x * scale); op[1] = f2bf(v.y * scale);
  op[2] = f2bf(v.z * scale); op[3] = f2bf(v.w * scale);
}

// ---------------------------------------------------------------------------
// 2) f32 -> bf16 cast, 4 elems/thread
// ---------------------------------------------------------------------------
__global__ __launch_bounds__(256) void k_cast(const float* __restrict__ X,
                                              unsigned short* __restrict__ Xb) {
  const int i = blockIdx.x * 256 + threadIdx.x;
  const float4 v = ((const float4*)X)[i];
  ushort4 o = { f2bf(v.x), f2bf(v.y), f2bf(v.z), f2bf(v.w) };
  ((ushort4*)Xb)[i] = o;
}

// ---------------------------------------------------------------------------
// 3) C[M][N] = A[M][K] * B[N][K]^T   (bf16 in, f32 acc), 128x128x64 tile, 4 waves
// ---------------------------------------------------------------------------
#define LDP 88
template <int WRITE_BF16>
__global__ __launch_bounds__(256) void k_gemm_bt(const unsigned short* __restrict__ A,
                                                 const unsigned short* __restrict__ Bm,
                                                 void* __restrict__ Cv,
                                                 int M, int N, int K) {
  __shared__ unsigned short As[128 * LDP];
  __shared__ unsigned short Bs[128 * LDP];
  const int tid = threadIdx.x;
  const int nbn = N >> 7;
  const int bm = (blockIdx.x / nbn) << 7;
  const int bn = (blockIdx.x % nbn) << 7;
  const int wave = tid >> 6, lane = tid & 63;
  const int wr = (wave >> 1) << 6, wc = (wave & 1) << 6;
  const int l16 = lane & 15, lg = lane >> 4;

  f32x4 acc[4][4];
#pragma unroll
  for (int m = 0; m < 4; ++m)
#pragma unroll
    for (int n = 0; n < 4; ++n) acc[m][n] = (f32x4){0.f, 0.f, 0.f, 0.f};

  for (int k0 = 0; k0 < K; k0 += 64) {
    s16x8 ra[4], rb[4];
#pragma unroll
    for (int it = 0; it < 4; ++it) {
      const int c = it * 256 + tid;
      const int r = c >> 3, col = (c & 7) << 3;
      ra[it] = *(const s16x8*)(A + (size_t)(bm + r) * K + k0 + col);
      rb[it] = *(const s16x8*)(Bm + (size_t)(bn + r) * K + k0 + col);
    }
    __syncthreads();
#pragma unroll
    for (int it = 0; it < 4; ++it) {
      const int c = it * 256 + tid;
      const int r = c >> 3, col = (c & 7) << 3;
      *(s16x8*)(As + r * LDP + col) = ra[it];
      *(s16x8*)(Bs + r * LDP + col) = rb[it];
    }
    __syncthreads();
#pragma unroll
    for (int ks = 0; ks < 2; ++ks) {
      s16x8 af[4], bq[4];
#pragma unroll
      for (int m = 0; m < 4; ++m)
        af[m] = *(const s16x8*)(As + (wr + m * 16 + l16) * LDP + ks * 32 + lg * 8);
#pragma unroll
      for (int n = 0; n < 4; ++n)
        bq[n] = *(const s16x8*)(Bs + (wc + n * 16 + l16) * LDP + ks * 32 + lg * 8);
#pragma unroll
      for (int m = 0; m < 4; ++m)
#pragma unroll
        for (int n = 0; n < 4; ++n)
          acc[m][n] = __builtin_amdgcn_mfma_f32_16x16x32_bf16(af[m], bq[n], acc[m][n], 0, 0, 0);
    }
  }
  if (WRITE_BF16) {
    unsigned short* C = (unsigned short*)Cv;
#pragma unroll
    for (int m = 0; m < 4; ++m)
#pragma unroll
      for (int n = 0; n < 4; ++n)
#pragma unroll
        for (int r = 0; r < 4; ++r)
          C[(size_t)(bm + wr + m * 16 + lg * 4 + r) * N + (bn + wc + n * 16 + l16)] =
              f2bf(acc[m][n][r]);
  } else {
    float* C = (float*)Cv;
#pragma unroll
    for (int m = 0; m < 4; ++m)
#pragma unroll
      for (int n = 0; n < 4; ++n)
#pragma unroll
        for (int r = 0; r < 4; ++r)
          C[(size_t)(bm + wr + m * 16 + lg * 4 + r) * N + (bn + wc + n * 16 + l16)] =
              acc[m][n][r];
  }
}

// ---------------------------------------------------------------------------
// 4) normalize q,k head-vectors (hd=64) in-place; q rows get the extra 1/8
//    attention scale folded in (power of two -> exact in bf16)
// ---------------------------------------------------------------------------
__global__ __launch_bounds__(256) void k_qknorm(unsigned short* __restrict__ qkv) {
  const int row = blockIdx.x, tid = threadIdx.x;
  const int hv = tid >> 3, g = tid & 7;   // 32 head-vectors (16 q + 16 k)
  const int base = (hv < 16) ? (hv * HDIM) : (DMODEL + (hv - 16) * HDIM);
  unsigned short* p = qkv + (size_t)row * QKVC + base + g * 8;
  s16x8 v = *(const s16x8*)p;
  float f[8];
  float ss = 0.f;
#pragma unroll
  for (int j = 0; j < 8; ++j) { f[j] = bf2f((unsigned short)v[j]); ss += f[j] * f[j]; }
  ss += __shfl_xor(ss, 1); ss += __shfl_xor(ss, 2); ss += __shfl_xor(ss, 4);
  float scale = 1.f / (1e-4f + sqrtf(ss) * 0.125f);
  if (hv < 16) scale *= 0.125f;           // fold attn 1/sqrt(hd)
  s16x8 o;
#pragma unroll
  for (int j = 0; j < 8; ++j) o[j] = (short)f2bf(f[j] * scale);
  *(s16x8*)p = o;
}

// ---------------------------------------------------------------------------
// 5) V transpose: qkv v-part -> Vt[bh][d][t]
// ---------------------------------------------------------------------------
__global__ __launch_bounds__(256) void k_vtrans(const unsigned short* __restrict__ qkv,
                                                unsigned short* __restrict__ Vt) {
  const int tt = blockIdx.x & 31, bh = blockIdx.x >> 5;
  const int b = bh >> 4, h = bh & 15;
  const int t0 = tt * 64;
  __shared__ unsigned short tile[64][80];
  const int tid = threadIdx.x;
#pragma unroll
  for (int half = 0; half < 2; ++half) {
    const int tl = half * 32 + (tid >> 3), part = tid & 7;
    s16x8 v = *(const s16x8*)(qkv + (size_t)(b * SEQ + t0 + tl) * QKVC + 2 * DMODEL +
                              h * HDIM + part * 8);
    *(s16x8*)(&tile[tl][part * 8]) = v;
  }
  __syncthreads();
#pragma unroll
  for (int half = 0; half < 2; ++half) {
    const int d = half * 32 + (tid >> 3), tp = tid & 7;
    s16x8 o;
#pragma unroll
    for (int j = 0; j < 8; ++j) o[j] = (short)tile[tp * 8 + j][d];
    *(s16x8*)(Vt + (size_t)(bh * HDIM + d) * SEQ + t0 + tp * 8) = o;
  }
}

// ---------------------------------------------------------------------------
// 6) flash attention, SWAPPED-operand form: S^T = mfma(K,Q) so each lane's
//    16 S-values all belong to one query (q = l16). Row reduce = in-register
//    + 2 shuffles. PV computed as O^T = mfma(V^T, P^T); P^T repacked through
//    wave-private LDS ([q][64key], stride 72 shorts).
// ---------------------------------------------------------------------------
#define PST 72
__global__ __launch_bounds__(256) void k_attn(const unsigned short* __restrict__ qkv,
                                              const unsigned short* __restrict__ Vt,
                                              unsigned short* __restrict__ O) {
  const int qt = blockIdx.x & 31, bh = blockIdx.x >> 5;
  const int b = bh >> 4, h = bh & 15;
  const int wave = threadIdx.x >> 6, lane = threadIdx.x & 63;
  const int l16 = lane & 15, lg = lane >> 4;
  const int q0 = qt * 64 + wave * 16;

  __shared__ unsigned short P[4][16 * PST];
  unsigned short* Pw = &P[wave][0];

  // Q fragments (B operand: col=q=l16, k=8*lg+j); 1/8 scale pre-folded
  const size_t qbase = (size_t)(b * SEQ + q0 + l16) * QKVC + h * HDIM;
  const s16x8 aq0 = *(const s16x8*)(qkv + qbase + lg * 8);
  const s16x8 aq1 = *(const s16x8*)(qkv + qbase + 32 + lg * 8);

  f32x4 o[4];
#pragma unroll
  for (int n = 0; n < 4; ++n) o[n] = (f32x4){0.f, 0.f, 0.f, 0.f};
  float m = -1e30f, l = 0.f;

  for (int kt = 0; kt < SEQ; kt += 64) {
    // ---- S^T = K * Q^T  (rows = keys, cols = queries) ----
    f32x4 st[4];
    __builtin_amdgcn_s_setprio(1);
#pragma unroll
    for (int sub = 0; sub < 4; ++sub) {
      const size_t kbase =
          (size_t)(b * SEQ + kt + sub * 16 + l16) * QKVC + DMODEL + h * HDIM;
      const s16x8 bk0 = *(const s16x8*)(qkv + kbase + lg * 8);
      const s16x8 bk1 = *(const s16x8*)(qkv + kbase + 32 + lg * 8);
      f32x4 z = (f32x4){0.f, 0.f, 0.f, 0.f};
      z = __builtin_amdgcn_mfma_f32_16x16x32_bf16(bk0, aq0, z, 0, 0, 0);
      z = __builtin_amdgcn_mfma_f32_16x16x32_bf16(bk1, aq1, z, 0, 0, 0);
      st[sub] = z;
    }
    __builtin_amdgcn_s_setprio(0);
    // ---- prefetch V fragments (A operand rows = d) for this key tile ----
    s16x8 bv0[4], bv1[4];
#pragma unroll
    for (int n = 0; n < 4; ++n) {
      const size_t vbase = (size_t)(bh * HDIM + n * 16 + l16) * SEQ + kt;
      bv0[n] = *(const s16x8*)(Vt + vbase + lg * 8);
      bv1[n] = *(const s16x8*)(Vt + vbase + 32 + lg * 8);
    }
    // ---- online softmax: all 16 values in-lane belong to q = l16 ----
    float tm = fmaxf(fmaxf(fmaxf(st[0][0], st[0][1]), fmaxf(st[0][2], st[0][3])),
                     fmaxf(fmaxf(st[1][0], st[1][1]), fmaxf(st[1][2], st[1][3])));
    tm = fmaxf(tm, fmaxf(fmaxf(fmaxf(st[2][0], st[2][1]), fmaxf(st[2][2], st[2][3])),
                         fmaxf(fmaxf(st[3][0], st[3][1]), fmaxf(st[3][2], st[3][3]))));
    tm = fmaxf(tm, __shfl_xor(tm, 16));
    tm = fmaxf(tm, __shfl_xor(tm, 32));
    const float mnew = fmaxf(m, tm);
    const float c = __expf(m - mnew);
    m = mnew;
    float rs = 0.f;
#pragma unroll
    for (int sub = 0; sub < 4; ++sub)
#pragma unroll
      for (int r = 0; r < 4; ++r) {
        const float pv = __expf(st[sub][r] - mnew);
        st[sub][r] = pv;
        rs += pv;
      }
    rs += __shfl_xor(rs, 16);
    rs += __shfl_xor(rs, 32);
    l = l * c + rs;
#pragma unroll
    for (int n = 0; n < 4; ++n) o[n] *= c;
    // ---- P^T -> LDS [q][key] (b64 writes), read back as B-frags (b128) ----
#pragma unroll
    for (int sub = 0; sub < 4; ++sub) {
      s16x4 pk = { (short)f2bf(st[sub][0]), (short)f2bf(st[sub][1]),
                   (short)f2bf(st[sub][2]), (short)f2bf(st[sub][3]) };
      *(s16x4*)(Pw + l16 * PST + sub * 16 + lg * 4) = pk;
    }
    const s16x8 pa0 = *(const s16x8*)(Pw + l16 * PST + lg * 8);
    const s16x8 pa1 = *(const s16x8*)(Pw + l16 * PST + 32 + lg * 8);
    // ---- O^T += V^T * P^T ----
    __builtin_amdgcn_s_setprio(1);
#pragma unroll
    for (int n = 0; n < 4; ++n) {
      o[n] = __builtin_amdgcn_mfma_f32_16x16x32_bf16(bv0[n], pa0, o[n], 0, 0, 0);
      o[n] = __builtin_amdgcn_mfma_f32_16x16x32_bf16(bv1[n], pa1, o[n], 0, 0, 0);
    }
    __builtin_amdgcn_s_setprio(0);
  }
  // ---- epilogue: O^T[d][q] regs -> O[b][t=q][h*64+d], 4 consecutive d ----
  const float inv = 1.f / l;
#pragma unroll
  for (int n = 0; n < 4; ++n) {
    s16x4 ov = { (short)f2bf(o[n][0] * inv), (short)f2bf(o[n][1] * inv),
                 (short)f2bf(o[n][2] * inv), (short)f2bf(o[n][3] * inv) };
    *(s16x4*)(O + (size_t)(b * SEQ + q0 + l16) * DMODEL + h * HDIM + n * 16 + lg * 4) = ov;
  }
}

// ---------------------------------------------------------------------------
// launch: ws layout (bytes): Wq[0,6M) Wo[6M,8M) Xb[8M,16M) QKV[16M,40M) Vt[40M,48M)
// ---------------------------------------------------------------------------
extern "C" void kernel_launch(void* const* d_in, const int* in_sizes, int n_in,
                              void* d_out, int out_size, void* d_ws, size_t ws_size,
                              hipStream_t stream) {
  const float* x    = (const float*)d_in[0];
  const float* wqkv = (const float*)d_in[1];
  const float* wout = (const float*)d_in[2];
  char* ws = (char*)d_ws;
  unsigned short* Wq  = (unsigned short*)(ws);
  unsigned short* Wo  = (unsigned short*)(ws + 6291456);
  unsigned short* Xb  = (unsigned short*)(ws + 8388608);
  unsigned short* QKV = (unsigned short*)(ws + 16777216);
  unsigned short* Vt  = (unsigned short*)(ws + 41943040);
  (void)in_sizes; (void)n_in; (void)out_size; (void)ws_size;

  k_wnorm<<<QKVC, 256, 0, stream>>>(wqkv, Wq);
  k_wnorm<<<DMODEL, 256, 0, stream>>>(wout, Wo);
  k_cast<<<(NROWS * DMODEL) / 1024, 256, 0, stream>>>(x, Xb);
  k_gemm_bt<1><<<(NROWS / 128) * (QKVC / 128), 256, 0, stream>>>(
      Xb, Wq, (void*)QKV, NROWS, QKVC, DMODEL);
  k_qknorm<<<NROWS, 256, 0, stream>>>(QKV);
  k_vtrans<<<BATCH * NHEAD * (SEQ / 64), 256, 0, stream>>>(QKV, Vt);
  k_attn<<<BATCH * NHEAD * (SEQ / 64), 256, 0, stream>>>(QKV, Vt, Xb);
  k_gemm_bt<0><<<(NROWS / 128) * (DMODEL / 128), 256, 0, stream>>>(
      Xb, Wo, d_out, NROWS, DMODEL, DMODEL);
}